// Round 1
// 463.115 us; speedup vs baseline: 1.1370x; 1.1370x over previous
//
#include <hip/hip_runtime.h>
#include <hip/hip_bf16.h>
#include <stdint.h>

#define B2 8192
#define D  512
#define K2 1024        // [hi(x^2) | hi(x)] vs [inv | -2x*inv], single fp16 product
#define NM1 (B2 - 1)   // 8191
#define NT  16         // K-tiles of 64

typedef _Float16 f16;
typedef _Float16 f16x2 __attribute__((ext_vector_type(2)));
typedef _Float16 f16x8 __attribute__((ext_vector_type(8)));
typedef float    f32x4 __attribute__((ext_vector_type(4)));

// ---------------------------------------------------------------------------
// prep (fused): per row i (one block), build fp16 GEMM operands, plus
//   rowc[i]  = 0.1*gt[i] + 0.5*ls[i]          (gt computed exactly in fp32)
//   colc2[i] = -0.5*ls[pos(i)] - 0.1*t3[i]
//   rowsum[i] = 0
// ---------------------------------------------------------------------------
__global__ __launch_bounds__(256) void prep(
    const float* __restrict__ feat, const float* __restrict__ sig,
    const int* __restrict__ label,
    f16* __restrict__ Ahat, f16* __restrict__ Bhat,
    float* __restrict__ rowc, float* __restrict__ colc2, float* __restrict__ rowsum)
{
    int i = blockIdx.x;
    int t = threadIdx.x;
    int lb = label[i];
    int p  = lb + (lb >= i ? 1 : 0);

    const float2 xv  = ((const float2*)(feat + (size_t)i * D))[t];
    const float2 sv  = ((const float2*)(sig  + (size_t)i * D))[t];
    const float2 xpv = ((const float2*)(feat + (size_t)p * D))[t];
    const float2 spv = ((const float2*)(sig  + (size_t)p * D))[t];

    float inv0 = 1.0f / sv.x, inv1 = 1.0f / sv.y;
    float x20 = xv.x * xv.x, x21 = xv.y * xv.y;

    f16* Ar = Ahat + (size_t)i * K2;
    f16* Br = Bhat + (size_t)i * K2;
    *(f16x2*)&Ar[2 * t]       = f16x2{(f16)x20, (f16)x21};
    *(f16x2*)&Ar[512 + 2 * t] = f16x2{(f16)xv.x, (f16)xv.y};
    *(f16x2*)&Br[2 * t]       = f16x2{(f16)inv0, (f16)inv1};
    *(f16x2*)&Br[512 + 2 * t] = f16x2{(f16)(-2.0f * xv.x * inv0), (f16)(-2.0f * xv.y * inv1)};

    float t3p = x20 * inv0 + x21 * inv1;
    float lsp = __logf(sv.x) + __logf(sv.y);
    float lpp = __logf(spv.x) + __logf(spv.y);
    float dx0 = xv.x - xpv.x, dx1 = xv.y - xpv.y;
    float gtp = dx0 * dx0 / spv.x + dx1 * dx1 / spv.y;

    for (int off = 32; off; off >>= 1) {
        t3p += __shfl_down(t3p, off);
        lsp += __shfl_down(lsp, off);
        lpp += __shfl_down(lpp, off);
        gtp += __shfl_down(gtp, off);
    }
    __shared__ float w0[4], w1[4], w2[4], w3[4];
    int lane = t & 63, w = t >> 6;
    if (lane == 0) { w0[w] = t3p; w1[w] = lsp; w2[w] = lpp; w3[w] = gtp; }
    __syncthreads();
    if (t == 0) {
        float t3 = w0[0] + w0[1] + w0[2] + w0[3];
        float ls = w1[0] + w1[1] + w1[2] + w1[3];
        float lp = w2[0] + w2[1] + w2[2] + w2[3];
        float gt = w3[0] + w3[1] + w3[2] + w3[3];
        rowc[i]  = 0.1f * gt + 0.5f * ls;
        colc2[i] = -0.5f * lp - 0.1f * t3;
        rowsum[i] = 0.0f;
    }
}

// ---------------------------------------------------------------------------
// Fused GEMM (M=N=8192, K=1024, fp16 MFMA 16x16x32) + exp epilogue + row sums.
// 256x256 tile / block, 8 waves (2M x 4N), each wave 8x4 MFMA frags (128x64).
// BK=64, 8-phase counted-vmcnt schedule (T3+T4), XOR chunk swizzle (T2),
// s_setprio around MFMA clusters (T5), chunked XCD block mapping (T1).
//
// LDS: As/Bs double-buffered [2][256][64] f16 (128 KiB) + rS/cS (2 KiB).
// Half-tiles: hA0 = A rows 0-127, hA1 = 128-255 (2 x glds/thread each); same B.
// Staging schedule per quad computing tile T in buf b (issue order matters,
// vmcnt is a FIFO count -- per-wave, 2 loads per half-tile):
//   p0: issue hA0[T+1] -> buf b^1   (A[b^1] fully consumed last quad)
//   p1: issue hA1[T+1] -> buf b^1 ; then hB0[T+2] -> buf b (B[b] read in p0 only)
//   p2: issue hB1[T+2] -> buf b
//   p3: s_waitcnt vmcnt(4)  => last 4 outstanding = hB*[T+2]; everything of
//       tile T+1 (hA issued this quad, hB issued last quad) has landed.
// ---------------------------------------------------------------------------

#define GLDS16(src, dst)                                                       \
  __builtin_amdgcn_global_load_lds(                                            \
      (const __attribute__((address_space(1))) unsigned int*)(src),            \
      (__attribute__((address_space(3))) unsigned int*)(dst), 16, 0, 0)

// one half-tile (128 rows x 64 cols f16): 2 loads/thread, r=0/1 -> +64 rows.
// dest is wave-uniform base + lane*16B (HW adds lane offset).
#define STAGE_HALF(gbase, hrow, koff, dstbase)                                 \
  do {                                                                         \
    GLDS16((gbase) + (size_t)(hrow) * K2 + (koff), (dstbase) + w512);          \
    GLDS16((gbase) + (size_t)((hrow) + 64) * K2 + (koff),                      \
           (dstbase) + 4096 + w512);                                           \
  } while (0)

template <int VM>
__device__ __forceinline__ void kquad(
    const f16* Asb, const f16* Bsb,      // buffers being computed (tile T)
    f16* AsN,                            // A stage dest  = other buffer (T+1)
    f16* BsC,                            // B stage dest  = same buffer  (T+2)
    const f16* gA, const f16* gB, int w512,
    int doA, int kA, int doB, int kB,
    int wr128, int wc64, int l15, int lhi, int l7,
    f32x4 (&acc)[8][4])
{
    f16x8 bf[4][2], af[2][2];

    // ---- phase 0: all B frags + A rows [0,32); stage hA0[T+1] ----
    #pragma unroll
    for (int ni = 0; ni < 4; ++ni)
        #pragma unroll
        for (int ks = 0; ks < 2; ++ks)
            bf[ni][ks] = *(const f16x8*)&Bsb[(wc64 + ni * 16 + l15) * 64 +
                                             (((ks * 4 + lhi) ^ l7) * 8)];
    #pragma unroll
    for (int m = 0; m < 2; ++m)
        #pragma unroll
        for (int ks = 0; ks < 2; ++ks)
            af[m][ks] = *(const f16x8*)&Asb[(wr128 + m * 16 + l15) * 64 +
                                            (((ks * 4 + lhi) ^ l7) * 8)];
    if (doA) { STAGE_HALF(gA, 0, kA, AsN); }
    asm volatile("" ::: "memory");
    __builtin_amdgcn_s_barrier();
    asm volatile("s_waitcnt lgkmcnt(0)" ::: "memory");
    __builtin_amdgcn_sched_barrier(0);
    __builtin_amdgcn_s_setprio(1);
    #pragma unroll
    for (int m = 0; m < 2; ++m)
        #pragma unroll
        for (int ni = 0; ni < 4; ++ni)
            #pragma unroll
            for (int ks = 0; ks < 2; ++ks)
                acc[m][ni] = __builtin_amdgcn_mfma_f32_16x16x32_f16(
                    af[m][ks], bf[ni][ks], acc[m][ni], 0, 0, 0);
    __builtin_amdgcn_s_setprio(0);
    __builtin_amdgcn_s_barrier();

    // ---- phase 1: A rows [32,64); stage hA1[T+1], then hB0[T+2] ----
    #pragma unroll
    for (int m = 0; m < 2; ++m)
        #pragma unroll
        for (int ks = 0; ks < 2; ++ks)
            af[m][ks] = *(const f16x8*)&Asb[(wr128 + (2 + m) * 16 + l15) * 64 +
                                            (((ks * 4 + lhi) ^ l7) * 8)];
    if (doA) { STAGE_HALF(gA, 128, kA, AsN + 8192); }
    asm volatile("" ::: "memory");   // keep hA1 issue before hB0 (vmcnt FIFO)
    if (doB) { STAGE_HALF(gB, 0, kB, BsC); }
    asm volatile("" ::: "memory");
    __builtin_amdgcn_s_barrier();
    asm volatile("s_waitcnt lgkmcnt(0)" ::: "memory");
    __builtin_amdgcn_sched_barrier(0);
    __builtin_amdgcn_s_setprio(1);
    #pragma unroll
    for (int m = 0; m < 2; ++m)
        #pragma unroll
        for (int ni = 0; ni < 4; ++ni)
            #pragma unroll
            for (int ks = 0; ks < 2; ++ks)
                acc[2 + m][ni] = __builtin_amdgcn_mfma_f32_16x16x32_f16(
                    af[m][ks], bf[ni][ks], acc[2 + m][ni], 0, 0, 0);
    __builtin_amdgcn_s_setprio(0);
    __builtin_amdgcn_s_barrier();

    // ---- phase 2: A rows [64,96); stage hB1[T+2] ----
    #pragma unroll
    for (int m = 0; m < 2; ++m)
        #pragma unroll
        for (int ks = 0; ks < 2; ++ks)
            af[m][ks] = *(const f16x8*)&Asb[(wr128 + (4 + m) * 16 + l15) * 64 +
                                            (((ks * 4 + lhi) ^ l7) * 8)];
    if (doB) { STAGE_HALF(gB, 128, kB, BsC + 8192); }
    asm volatile("" ::: "memory");
    __builtin_amdgcn_s_barrier();
    asm volatile("s_waitcnt lgkmcnt(0)" ::: "memory");
    __builtin_amdgcn_sched_barrier(0);
    __builtin_amdgcn_s_setprio(1);
    #pragma unroll
    for (int m = 0; m < 2; ++m)
        #pragma unroll
        for (int ni = 0; ni < 4; ++ni)
            #pragma unroll
            for (int ks = 0; ks < 2; ++ks)
                acc[4 + m][ni] = __builtin_amdgcn_mfma_f32_16x16x32_f16(
                    af[m][ks], bf[ni][ks], acc[4 + m][ni], 0, 0, 0);
    __builtin_amdgcn_s_setprio(0);
    __builtin_amdgcn_s_barrier();

    // ---- phase 3: A rows [96,128); no stage; counted vmcnt ----
    #pragma unroll
    for (int m = 0; m < 2; ++m)
        #pragma unroll
        for (int ks = 0; ks < 2; ++ks)
            af[m][ks] = *(const f16x8*)&Asb[(wr128 + (6 + m) * 16 + l15) * 64 +
                                            (((ks * 4 + lhi) ^ l7) * 8)];
    __builtin_amdgcn_s_barrier();
    asm volatile("s_waitcnt lgkmcnt(0)" ::: "memory");
    __builtin_amdgcn_sched_barrier(0);
    __builtin_amdgcn_s_setprio(1);
    #pragma unroll
    for (int m = 0; m < 2; ++m)
        #pragma unroll
        for (int ni = 0; ni < 4; ++ni)
            #pragma unroll
            for (int ks = 0; ks < 2; ++ks)
                acc[6 + m][ni] = __builtin_amdgcn_mfma_f32_16x16x32_f16(
                    af[m][ks], bf[ni][ks], acc[6 + m][ni], 0, 0, 0);
    __builtin_amdgcn_s_setprio(0);
    if (VM == 4) asm volatile("s_waitcnt vmcnt(4)" ::: "memory");
    else         asm volatile("s_waitcnt vmcnt(0)" ::: "memory");
    __builtin_amdgcn_s_barrier();
}

__global__ __launch_bounds__(512, 1) void gemm_epilogue(
    const f16* __restrict__ Ahat, const f16* __restrict__ Bhat,
    const float* __restrict__ rowc, const float* __restrict__ colc2,
    float* __restrict__ rowsum, float* __restrict__ out)
{
    __shared__ f16 As[2][256 * 64];   // 64 KiB
    __shared__ f16 Bs[2][256 * 64];   // 64 KiB
    __shared__ float rS[256], cS[256];

    // chunked XCD mapping: xcd = bid&7 owns bm in [4x,4x+4) x all bn;
    // within the chunk B panels are reused 4x back-to-back, A stays L2-resident.
    int bid = blockIdx.x;
    int rr = bid >> 3, x = bid & 7;
    int bm = x * 4 + (rr & 3);        // 0..31
    int bn = rr >> 2;                 // 0..31

    int t = threadIdx.x;
    int l = t & 63, w = t >> 6;       // 8 waves
    int wr128 = (w >> 2) * 128;       // wave M-offset (2 rows of waves)
    int wc64  = (w & 3) * 64;         // wave N-offset (4 cols of waves)
    int l15 = l & 15, lhi = l >> 4, l7 = l & 7;
    int w512 = w * 512;               // f16 units: per-wave 1 KiB staging slot

    // per-thread staging source: row t>>3 (+r*64 +h*128), chunk (t&7)^((t>>3)&7)
    int gcs = (t & 7) ^ ((t >> 3) & 7);
    const f16* gA = Ahat + (size_t)(bm * 256 + (t >> 3)) * K2 + gcs * 8;
    const f16* gB = Bhat + (size_t)(bn * 256 + (t >> 3)) * K2 + gcs * 8;

    // row/col constants -> LDS (before any counted-vmcnt region)
    if (t < 256) rS[t]       = rowc[bm * 256 + t];
    else         cS[t - 256] = colc2[bn * 256 + (t - 256)];

    // prologue: tile0 (A+B) -> buf0; hB[1] -> buf1; full drain once.
    STAGE_HALF(gA, 0,   0,  &As[0][0]);
    STAGE_HALF(gA, 128, 0,  &As[0][8192]);
    STAGE_HALF(gB, 0,   0,  &Bs[0][0]);
    STAGE_HALF(gB, 128, 0,  &Bs[0][8192]);
    STAGE_HALF(gB, 0,   64, &Bs[1][0]);
    STAGE_HALF(gB, 128, 64, &Bs[1][8192]);
    __syncthreads();

    f32x4 acc[8][4];
    #pragma unroll
    for (int a = 0; a < 8; ++a)
        #pragma unroll
        for (int b = 0; b < 4; ++b) acc[a][b] = f32x4{0.f, 0.f, 0.f, 0.f};

    // steady state: tiles 0..13 (guards all true), then peeled tail 14,15.
    #pragma unroll 1
    for (int it = 0; it < 7; ++it) {
        int T = 2 * it;
        kquad<4>(&As[0][0], &Bs[0][0], &As[1][0], &Bs[0][0], gA, gB, w512,
                 1, (T + 1) * 64, 1, (T + 2) * 64,
                 wr128, wc64, l15, lhi, l7, acc);
        kquad<4>(&As[1][0], &Bs[1][0], &As[0][0], &Bs[1][0], gA, gB, w512,
                 1, (T + 2) * 64, 1, (T + 3) * 64,
                 wr128, wc64, l15, lhi, l7, acc);
    }
    kquad<0>(&As[0][0], &Bs[0][0], &As[1][0], &Bs[0][0], gA, gB, w512,
             1, 15 * 64, 0, 0, wr128, wc64, l15, lhi, l7, acc);
    kquad<0>(&As[1][0], &Bs[1][0], &As[0][0], &Bs[1][0], gA, gB, w512,
             0, 0, 0, 0, wr128, wc64, l15, lhi, l7, acc);

    // epilogue: exp + skip-diag scatter + row sums (C/D: row=quad*4+rg, col=l&15)
    int qd = l >> 4, lc = l & 15;
    #pragma unroll
    for (int mi = 0; mi < 8; ++mi) {
        #pragma unroll
        for (int rg = 0; rg < 4; ++rg) {
            int il = wr128 + mi * 16 + qd * 4 + rg;
            int i  = bm * 256 + il;
            float rc = rS[il];
            float part = 0.f;
            #pragma unroll
            for (int ni = 0; ni < 4; ++ni) {
                int jl = wc64 + ni * 16 + lc;
                int j  = bn * 256 + jl;
                float v = __expf(rc - 0.1f * acc[mi][ni][rg] + cS[jl]);
                if (j != i) {
                    out[1 + (size_t)i * NM1 + (j - (j > i ? 1 : 0))] = v;
                    part += v;
                }
            }
            part += __shfl_xor(part, 1);
            part += __shfl_xor(part, 2);
            part += __shfl_xor(part, 4);
            part += __shfl_xor(part, 8);
            if (lc == 0) atomicAdd(&rowsum[i], part);
        }
    }
}

// ---------------------------------------------------------------------------
// loss = mean_i log(rowsum[i]) -> out[0]
// ---------------------------------------------------------------------------
__global__ __launch_bounds__(256) void loss_k(const float* __restrict__ rowsum,
                                              float* __restrict__ out)
{
    int t = threadIdx.x;
    float s = 0.f;
    for (int r = t; r < B2; r += 256) s += __logf(rowsum[r]);
    for (int off = 32; off; off >>= 1) s += __shfl_down(s, off);
    __shared__ float wv[4];
    if ((t & 63) == 0) wv[t >> 6] = s;
    __syncthreads();
    if (t == 0) out[0] = (wv[0] + wv[1] + wv[2] + wv[3]) * (1.0f / (float)B2);
}

extern "C" void kernel_launch(void* const* d_in, const int* in_sizes, int n_in,
                              void* d_out, int out_size, void* d_ws, size_t ws_size,
                              hipStream_t stream) {
    const float* feat  = (const float*)d_in[0];
    const float* sig   = (const float*)d_in[1];
    const int*   label = (const int*)d_in[2];
    float* out = (float*)d_out;

    char* ws = (char*)d_ws;
    f16* Ahat = (f16*)ws;                                  // 16 MB
    f16* Bhat = (f16*)(ws + (size_t)B2 * K2 * 2);          // 16 MB
    float* rowc   = (float*)(ws + (size_t)B2 * K2 * 4);
    float* colc2  = rowc + B2;
    float* rowsum = colc2 + B2;

    prep<<<dim3(B2), dim3(256), 0, stream>>>(feat, sig, label, Ahat, Bhat, rowc, colc2, rowsum);
    gemm_epilogue<<<dim3(1024), dim3(512), 0, stream>>>(Ahat, Bhat, rowc, colc2, rowsum, out);
    loss_k<<<dim3(1), dim3(256), 0, stream>>>(rowsum, out);
}

// Round 2
// 446.985 us; speedup vs baseline: 1.1781x; 1.0361x over previous
//
#include <hip/hip_runtime.h>
#include <hip/hip_bf16.h>
#include <stdint.h>

#define B2 8192
#define D  512
#define K2 1024        // [hi(x^2) | hi(x)] vs [inv | -2x*inv], single fp16 product
#define NM1 (B2 - 1)   // 8191

typedef _Float16 f16;
typedef _Float16 f16x2 __attribute__((ext_vector_type(2)));
typedef _Float16 f16x8 __attribute__((ext_vector_type(8)));
typedef float    f32x4 __attribute__((ext_vector_type(4)));

// ---------------------------------------------------------------------------
// prep (fused): per row i (one block), build fp16 GEMM operands, plus
//   rowc[i]  = 0.1*gt[i] + 0.5*ls[i]          (gt computed exactly in fp32)
//   colc2[i] = -0.5*ls[pos(i)] - 0.1*t3[i]
//   rowsum[i] = 0
// ---------------------------------------------------------------------------
__global__ __launch_bounds__(256) void prep(
    const float* __restrict__ feat, const float* __restrict__ sig,
    const int* __restrict__ label,
    f16* __restrict__ Ahat, f16* __restrict__ Bhat,
    float* __restrict__ rowc, float* __restrict__ colc2, float* __restrict__ rowsum)
{
    int i = blockIdx.x;
    int t = threadIdx.x;
    int lb = label[i];
    int p  = lb + (lb >= i ? 1 : 0);

    const float2 xv  = ((const float2*)(feat + (size_t)i * D))[t];
    const float2 sv  = ((const float2*)(sig  + (size_t)i * D))[t];
    const float2 xpv = ((const float2*)(feat + (size_t)p * D))[t];
    const float2 spv = ((const float2*)(sig  + (size_t)p * D))[t];

    float inv0 = 1.0f / sv.x, inv1 = 1.0f / sv.y;
    float x20 = xv.x * xv.x, x21 = xv.y * xv.y;

    f16* Ar = Ahat + (size_t)i * K2;
    f16* Br = Bhat + (size_t)i * K2;
    *(f16x2*)&Ar[2 * t]       = f16x2{(f16)x20, (f16)x21};
    *(f16x2*)&Ar[512 + 2 * t] = f16x2{(f16)xv.x, (f16)xv.y};
    *(f16x2*)&Br[2 * t]       = f16x2{(f16)inv0, (f16)inv1};
    *(f16x2*)&Br[512 + 2 * t] = f16x2{(f16)(-2.0f * xv.x * inv0), (f16)(-2.0f * xv.y * inv1)};

    float t3p = x20 * inv0 + x21 * inv1;
    float lsp = __logf(sv.x) + __logf(sv.y);
    float lpp = __logf(spv.x) + __logf(spv.y);
    float dx0 = xv.x - xpv.x, dx1 = xv.y - xpv.y;
    float gtp = dx0 * dx0 / spv.x + dx1 * dx1 / spv.y;

    for (int off = 32; off; off >>= 1) {
        t3p += __shfl_down(t3p, off);
        lsp += __shfl_down(lsp, off);
        lpp += __shfl_down(lpp, off);
        gtp += __shfl_down(gtp, off);
    }
    __shared__ float w0[4], w1[4], w2[4], w3[4];
    int lane = t & 63, w = t >> 6;
    if (lane == 0) { w0[w] = t3p; w1[w] = lsp; w2[w] = lpp; w3[w] = gtp; }
    __syncthreads();
    if (t == 0) {
        float t3 = w0[0] + w0[1] + w0[2] + w0[3];
        float ls = w1[0] + w1[1] + w1[2] + w1[3];
        float lp = w2[0] + w2[1] + w2[2] + w2[3];
        float gt = w3[0] + w3[1] + w3[2] + w3[3];
        rowc[i]  = 0.1f * gt + 0.5f * ls;
        colc2[i] = -0.5f * lp - 0.1f * t3;
        rowsum[i] = 0.0f;
    }
}

// ---------------------------------------------------------------------------
// Fused GEMM (M=N=8192, K=1024, fp16 MFMA 16x16x32) + exp epilogue + row sums.
// 256x256 tile / block, 8 waves (2M x 4N), each wave 8x4 MFMA frags (128x64).
//
// DEEP-SLACK staging (round-2 change): every staged datum is issued >= 6
// phases before its first read, fixing the A[T+1] ~2-phase-slack stall that
// left the K-loop additive (staging + LDS + MFMA) instead of overlapped.
//
// Key fact: phase p is the LAST reader of A-rows slice p of the current
// buffer (slice p = rows {32p..32p+32} u {128+32p..128+32p+32}); all B rows
// are read only in phase 0. So T+2 operands restage the CURRENT buffers
// right behind the reads:
//   p0: sliceA3[T+1] -> other A-buf        (1 glds/thread)
//   p1: sliceA0[T+2] -> cur A-buf; hB0[T+2] -> cur B-buf   (1+2)
//   p2: sliceA1[T+2] -> cur A-buf; hB1[T+2] -> cur B-buf   (1+2)
//   p3: sliceA2[T+2] -> cur A-buf          (1)
// One s_waitcnt vmcnt(7) per quad (after p3 MFMA): leaves exactly the 7
// p1-p3 issues outstanding, forcing sliceA3[T+1] + everything older (all of
// A[T+1], B[T+1]) complete -- exactly what quad T+1 reads. Tail: quad14
// vmcnt(0), quad15 stages nothing.
// ---------------------------------------------------------------------------

#define GLDS16(src, dst)                                                       \
  __builtin_amdgcn_global_load_lds(                                            \
      (const __attribute__((address_space(1))) unsigned int*)(src),            \
      (__attribute__((address_space(3))) unsigned int*)(dst), 16, 0, 0)

// 128-row half-tile (2 glds/thread): rows hrow+(t>>3) and +64.
#define STAGE_HALF(gbase, hrow, koff, dstbase)                                 \
  do {                                                                         \
    GLDS16((gbase) + (size_t)(hrow) * K2 + (koff), (dstbase) + w512);          \
    GLDS16((gbase) + (size_t)((hrow) + 64) * K2 + (koff),                      \
           (dstbase) + 4096 + w512);                                           \
  } while (0)

// 64-row A slice s = rows {32s+[0,32)} u {128+32s+[0,32)} (1 glds/thread).
// gAslice has the per-thread row split (grow0) and chunk swizzle built in;
// wbase = per-wave LDS row base for s=0 (waves 0-3 -> lower 32, 4-7 -> upper).
#define STAGE_ASLICE(gAslice, s, kk, dstbase)                                  \
  GLDS16((gAslice) + (size_t)(s) * 32 * K2 + (kk),                             \
         (dstbase) + (size_t)(wbase + 32 * (s)) * 64)

template <int VM>   // 7 = steady counted wait, 0 = tail drain, -1 = none
__device__ __forceinline__ void kquad(
    const f16* Asb, const f16* Bsb,   // buffers holding tile T
    f16* AsP,                         // other A-buf: sliceA3[T+1] dest
    f16* AsC, f16* BsC,               // current bufs: T+2 dest
    const f16* gAs, const f16* gB, int w512, int wbase,
    int doA3, int kA1,                // stage slice 3 of A[T+1]
    int doN,  int kN,                 // stage A-slices0-2 + B of tile T+2
    int wr128, int wc64, int l15, int lhi, int l7,
    f32x4 (&acc)[8][4])
{
    f16x8 bf[4][2], af[2][2];

    // ---- phase 0: all B frags + A slice 0; stage sliceA3[T+1] ----
    #pragma unroll
    for (int ni = 0; ni < 4; ++ni)
        #pragma unroll
        for (int ks = 0; ks < 2; ++ks)
            bf[ni][ks] = *(const f16x8*)&Bsb[(wc64 + ni * 16 + l15) * 64 +
                                             (((ks * 4 + lhi) ^ l7) * 8)];
    #pragma unroll
    for (int m = 0; m < 2; ++m)
        #pragma unroll
        for (int ks = 0; ks < 2; ++ks)
            af[m][ks] = *(const f16x8*)&Asb[(wr128 + m * 16 + l15) * 64 +
                                            (((ks * 4 + lhi) ^ l7) * 8)];
    if (doA3) { STAGE_ASLICE(gAs, 3, kA1, AsP); }
    asm volatile("" ::: "memory");
    __builtin_amdgcn_s_barrier();
    asm volatile("s_waitcnt lgkmcnt(0)" ::: "memory");
    __builtin_amdgcn_sched_barrier(0);
    __builtin_amdgcn_s_setprio(1);
    #pragma unroll
    for (int m = 0; m < 2; ++m)
        #pragma unroll
        for (int ni = 0; ni < 4; ++ni)
            #pragma unroll
            for (int ks = 0; ks < 2; ++ks)
                acc[m][ni] = __builtin_amdgcn_mfma_f32_16x16x32_f16(
                    af[m][ks], bf[ni][ks], acc[m][ni], 0, 0, 0);
    __builtin_amdgcn_s_setprio(0);
    __builtin_amdgcn_s_barrier();

    // ---- phase 1: A slice 1; stage sliceA0[T+2] + hB0[T+2] ----
    #pragma unroll
    for (int m = 0; m < 2; ++m)
        #pragma unroll
        for (int ks = 0; ks < 2; ++ks)
            af[m][ks] = *(const f16x8*)&Asb[(wr128 + (2 + m) * 16 + l15) * 64 +
                                            (((ks * 4 + lhi) ^ l7) * 8)];
    if (doN) {
        STAGE_ASLICE(gAs, 0, kN, AsC);
        STAGE_HALF(gB, 0, kN, BsC);
    }
    asm volatile("" ::: "memory");
    __builtin_amdgcn_s_barrier();
    asm volatile("s_waitcnt lgkmcnt(0)" ::: "memory");
    __builtin_amdgcn_sched_barrier(0);
    __builtin_amdgcn_s_setprio(1);
    #pragma unroll
    for (int m = 0; m < 2; ++m)
        #pragma unroll
        for (int ni = 0; ni < 4; ++ni)
            #pragma unroll
            for (int ks = 0; ks < 2; ++ks)
                acc[2 + m][ni] = __builtin_amdgcn_mfma_f32_16x16x32_f16(
                    af[m][ks], bf[ni][ks], acc[2 + m][ni], 0, 0, 0);
    __builtin_amdgcn_s_setprio(0);
    __builtin_amdgcn_s_barrier();

    // ---- phase 2: A slice 2; stage sliceA1[T+2] + hB1[T+2] ----
    #pragma unroll
    for (int m = 0; m < 2; ++m)
        #pragma unroll
        for (int ks = 0; ks < 2; ++ks)
            af[m][ks] = *(const f16x8*)&Asb[(wr128 + (4 + m) * 16 + l15) * 64 +
                                            (((ks * 4 + lhi) ^ l7) * 8)];
    if (doN) {
        STAGE_ASLICE(gAs, 1, kN, AsC);
        STAGE_HALF(gB, 128, kN, BsC + 8192);
    }
    asm volatile("" ::: "memory");
    __builtin_amdgcn_s_barrier();
    asm volatile("s_waitcnt lgkmcnt(0)" ::: "memory");
    __builtin_amdgcn_sched_barrier(0);
    __builtin_amdgcn_s_setprio(1);
    #pragma unroll
    for (int m = 0; m < 2; ++m)
        #pragma unroll
        for (int ni = 0; ni < 4; ++ni)
            #pragma unroll
            for (int ks = 0; ks < 2; ++ks)
                acc[4 + m][ni] = __builtin_amdgcn_mfma_f32_16x16x32_f16(
                    af[m][ks], bf[ni][ks], acc[4 + m][ni], 0, 0, 0);
    __builtin_amdgcn_s_setprio(0);
    __builtin_amdgcn_s_barrier();

    // ---- phase 3: A slice 3; stage sliceA2[T+2]; counted vmcnt ----
    #pragma unroll
    for (int m = 0; m < 2; ++m)
        #pragma unroll
        for (int ks = 0; ks < 2; ++ks)
            af[m][ks] = *(const f16x8*)&Asb[(wr128 + (6 + m) * 16 + l15) * 64 +
                                            (((ks * 4 + lhi) ^ l7) * 8)];
    if (doN) { STAGE_ASLICE(gAs, 2, kN, AsC); }
    asm volatile("" ::: "memory");
    __builtin_amdgcn_s_barrier();
    asm volatile("s_waitcnt lgkmcnt(0)" ::: "memory");
    __builtin_amdgcn_sched_barrier(0);
    __builtin_amdgcn_s_setprio(1);
    #pragma unroll
    for (int m = 0; m < 2; ++m)
        #pragma unroll
        for (int ni = 0; ni < 4; ++ni)
            #pragma unroll
            for (int ks = 0; ks < 2; ++ks)
                acc[6 + m][ni] = __builtin_amdgcn_mfma_f32_16x16x32_f16(
                    af[m][ks], bf[ni][ks], acc[6 + m][ni], 0, 0, 0);
    __builtin_amdgcn_s_setprio(0);
    if (VM == 7)      asm volatile("s_waitcnt vmcnt(7)" ::: "memory");
    else if (VM == 0) asm volatile("s_waitcnt vmcnt(0)" ::: "memory");
    __builtin_amdgcn_s_barrier();
}

__global__ __launch_bounds__(512, 1) void gemm_epilogue(
    const f16* __restrict__ Ahat, const f16* __restrict__ Bhat,
    const float* __restrict__ rowc, const float* __restrict__ colc2,
    float* __restrict__ rowsum, float* __restrict__ out)
{
    __shared__ f16 As[2][256 * 64];   // 64 KiB
    __shared__ f16 Bs[2][256 * 64];   // 64 KiB
    __shared__ float rS[256], cS[256];

    // chunked XCD mapping: xcd = bid&7 owns bm in [4x,4x+4) x all bn.
    int bid = blockIdx.x;
    int rr = bid >> 3, x = bid & 7;
    int bm = x * 4 + (rr & 3);        // 0..31
    int bn = rr >> 2;                 // 0..31

    int t = threadIdx.x;
    int l = t & 63, w = t >> 6;       // 8 waves
    int wr128 = (w >> 2) * 128;       // wave M-offset
    int wc64  = (w & 3) * 64;         // wave N-offset
    int l15 = l & 15, lhi = l >> 4, l7 = l & 7;
    int w512 = w * 512;               // half-tile staging: wave slot (f16)
    int wbase = 8 * w + (w >= 4 ? 96 : 0);   // A-slice staging: wave row base

    // staging source: row t>>3, chunk (t&7)^((t>>3)&7)  (LDS row % 8 swizzle)
    int gcs = (t & 7) ^ ((t >> 3) & 7);
    const f16* gA = Ahat + (size_t)(bm * 256 + (t >> 3)) * K2 + gcs * 8;
    const f16* gB = Bhat + (size_t)(bn * 256 + (t >> 3)) * K2 + gcs * 8;
    // A-slice source: split rows (t>>3)<32 -> lower group, else upper (+96)
    int grow0 = (t >> 3) + ((t >> 3) >= 32 ? 96 : 0);
    const f16* gAs = Ahat + (size_t)(bm * 256 + grow0) * K2 + gcs * 8;

    // row/col constants -> LDS
    if (t < 256) rS[t]       = rowc[bm * 256 + t];
    else         cS[t - 256] = colc2[bn * 256 + (t - 256)];

    // prologue: A[0], B[0], B[1] full; A[1] slices 0-2 (slice 3 at quad0.p0)
    STAGE_HALF(gA, 0,   0,  &As[0][0]);
    STAGE_HALF(gA, 128, 0,  &As[0][8192]);
    STAGE_HALF(gB, 0,   0,  &Bs[0][0]);
    STAGE_HALF(gB, 128, 0,  &Bs[0][8192]);
    STAGE_HALF(gB, 0,   64, &Bs[1][0]);
    STAGE_HALF(gB, 128, 64, &Bs[1][8192]);
    STAGE_ASLICE(gAs, 0, 64, &As[1][0]);
    STAGE_ASLICE(gAs, 1, 64, &As[1][0]);
    STAGE_ASLICE(gAs, 2, 64, &As[1][0]);
    __syncthreads();

    f32x4 acc[8][4];
    #pragma unroll
    for (int a = 0; a < 8; ++a)
        #pragma unroll
        for (int b = 0; b < 4; ++b) acc[a][b] = f32x4{0.f, 0.f, 0.f, 0.f};

    // quads 0..13 steady (vmcnt(7)), 14 drains, 15 stages nothing.
    #pragma unroll 1
    for (int it = 0; it < 7; ++it) {
        int T = 2 * it;
        kquad<7>(&As[0][0], &Bs[0][0], &As[1][0], &As[0][0], &Bs[0][0],
                 gAs, gB, w512, wbase, 1, (T + 1) * 64, 1, (T + 2) * 64,
                 wr128, wc64, l15, lhi, l7, acc);
        kquad<7>(&As[1][0], &Bs[1][0], &As[0][0], &As[1][0], &Bs[1][0],
                 gAs, gB, w512, wbase, 1, (T + 2) * 64, 1, (T + 3) * 64,
                 wr128, wc64, l15, lhi, l7, acc);
    }
    kquad<0>(&As[0][0], &Bs[0][0], &As[1][0], &As[0][0], &Bs[0][0],
             gAs, gB, w512, wbase, 1, 15 * 64, 0, 0,
             wr128, wc64, l15, lhi, l7, acc);
    kquad<-1>(&As[1][0], &Bs[1][0], &As[0][0], &As[1][0], &Bs[1][0],
              gAs, gB, w512, wbase, 0, 0, 0, 0,
              wr128, wc64, l15, lhi, l7, acc);

    // epilogue: exp + skip-diag scatter + row sums (C/D: row=quad*4+rg, col=l&15)
    int qd = l >> 4, lc = l & 15;
    #pragma unroll
    for (int mi = 0; mi < 8; ++mi) {
        #pragma unroll
        for (int rg = 0; rg < 4; ++rg) {
            int il = wr128 + mi * 16 + qd * 4 + rg;
            int i  = bm * 256 + il;
            float rc = rS[il];
            float part = 0.f;
            #pragma unroll
            for (int ni = 0; ni < 4; ++ni) {
                int jl = wc64 + ni * 16 + lc;
                int j  = bn * 256 + jl;
                float v = __expf(rc - 0.1f * acc[mi][ni][rg] + cS[jl]);
                if (j != i) {
                    out[1 + (size_t)i * NM1 + (j - (j > i ? 1 : 0))] = v;
                    part += v;
                }
            }
            part += __shfl_xor(part, 1);
            part += __shfl_xor(part, 2);
            part += __shfl_xor(part, 4);
            part += __shfl_xor(part, 8);
            if (lc == 0) atomicAdd(&rowsum[i], part);
        }
    }
}

// ---------------------------------------------------------------------------
// loss = mean_i log(rowsum[i]) -> out[0]
// ---------------------------------------------------------------------------
__global__ __launch_bounds__(256) void loss_k(const float* __restrict__ rowsum,
                                              float* __restrict__ out)
{
    int t = threadIdx.x;
    float s = 0.f;
    for (int r = t; r < B2; r += 256) s += __logf(rowsum[r]);
    for (int off = 32; off; off >>= 1) s += __shfl_down(s, off);
    __shared__ float wv[4];
    if ((t & 63) == 0) wv[t >> 6] = s;
    __syncthreads();
    if (t == 0) out[0] = (wv[0] + wv[1] + wv[2] + wv[3]) * (1.0f / (float)B2);
}

extern "C" void kernel_launch(void* const* d_in, const int* in_sizes, int n_in,
                              void* d_out, int out_size, void* d_ws, size_t ws_size,
                              hipStream_t stream) {
    const float* feat  = (const float*)d_in[0];
    const float* sig   = (const float*)d_in[1];
    const int*   label = (const int*)d_in[2];
    float* out = (float*)d_out;

    char* ws = (char*)d_ws;
    f16* Ahat = (f16*)ws;                                  // 16 MB
    f16* Bhat = (f16*)(ws + (size_t)B2 * K2 * 2);          // 16 MB
    float* rowc   = (float*)(ws + (size_t)B2 * K2 * 4);
    float* colc2  = rowc + B2;
    float* rowsum = colc2 + B2;

    prep<<<dim3(B2), dim3(256), 0, stream>>>(feat, sig, label, Ahat, Bhat, rowc, colc2, rowsum);
    gemm_epilogue<<<dim3(1024), dim3(512), 0, stream>>>(Ahat, Bhat, rowc, colc2, rowsum, out);
    loss_k<<<dim3(1), dim3(256), 0, stream>>>(rowsum, out);
}